// Round 17
// baseline (365.346 us; speedup 1.0000x reference)
//
#include <hip/hip_runtime.h>
#include <hip/hip_bf16.h>
#include <math.h>

#define NN 100000
#define DD 384
#define HH 128
#define KK 5

typedef __attribute__((ext_vector_type(8))) short short8;
typedef __attribute__((ext_vector_type(4))) float f32x4;

constexpr float INIT_VAL = 1.4142135623730951e-3f; // 1/sqrt(N*K)
constexpr float RSQRT5   = 0.44721359549995793f;   // 1/sqrt(5)

// f32 -> bf16 round-to-nearest-even
__device__ __forceinline__ ushort bf16rn(float x) {
    unsigned u = __float_as_uint(x);
    return (ushort)((u + 0x7FFFu + ((u >> 16) & 1u)) >> 16);
}

// ---------------- fused prep ----------------
// block 0: parallel fold qv @ W1[384:768] into bias; zero ssp + barrier counters
// blocks 1..24: pack W1[0:384] into B-fragment layout, bf16 RNE
// blocks 25..: transpose nbr to SoA + zero sA (mlp's scatter dest)
__global__ __launch_bounds__(256) void prep_kernel(
    const float* __restrict__ qv, const float* __restrict__ W1,
    const float* __restrict__ b1, const int* __restrict__ nbr,
    float* __restrict__ b1p, ushort* __restrict__ W1h,
    int* __restrict__ nbrT, float* __restrict__ sA,
    float* __restrict__ ssp, unsigned* __restrict__ cnt) {
    const int b = blockIdx.x, tid = threadIdx.x;
    if (b == 0) {
        __shared__ float part[256];
        const int h = tid & 127, half = tid >> 7;
        float s = 0.f;
        const float* Wq = W1 + (size_t)(DD + half * 192) * HH + h;
        const float* qh = qv + half * 192;
#pragma unroll 8
        for (int k = 0; k < 192; ++k)
            s = fmaf(qh[k], Wq[(size_t)k * HH], s);
        part[tid] = s;
        __syncthreads();
        if (tid < HH) b1p[tid] = part[tid] + part[tid + 128] + b1[tid];
        if (tid == 0) ssp[0] = 0.f;
        if (tid < 8) cnt[tid] = 0u;
    } else if (b <= 24) {
        int t = (b - 1) * 256 + tid;       // t = (c*12 + ks)*64 + lane, t < 6144
        int l = t & 63;
        int ks = (t >> 6) % 12;
        int c = (t >> 6) / 12;             // hidden 16-col block 0..7
        int k0 = ks * 32 + ((l >> 4) << 3);
        int col = c * 16 + (l & 15);
#pragma unroll
        for (int e = 0; e < 8; ++e)
            W1h[(size_t)t * 8 + e] = bf16rn(W1[(size_t)(k0 + e) * HH + col]);
    } else {
        int i = (b - 25) * 256 + tid;
        if (i < NN) {
#pragma unroll
            for (int j = 0; j < KK; ++j) {
                nbrT[j * NN + i] = nbr[i * KK + j];
                sA[j * NN + i] = 0.f;
            }
        }
    }
}

// ---------------- single-bf16 MFMA MLP (R13 exact, proven 86 us) + fused walk1 ----------------
__global__ __launch_bounds__(256) void mlp_mfma_kernel(
    const float* __restrict__ emb, const ushort* __restrict__ W1h,
    const float* __restrict__ b1p, const float* __restrict__ W2,
    const float* __restrict__ b2, const int* __restrict__ nbrT,
    float* __restrict__ gout /* [KK][NN] */, float* __restrict__ sA) {
    __shared__ __align__(16) ushort Ah[32 * 128];  // 8 KB
    __shared__ float pbuf[32][21];                 // 4 waves x 5 + pad

    const int tid = threadIdx.x;
    const int lane = tid & 63;
    const int wn = tid >> 6;   // col quarter 0..3
    const int blkBase = blockIdx.x * 32;

    f32x4 acc[2][2];
#pragma unroll
    for (int mt = 0; mt < 2; ++mt)
#pragma unroll
        for (int nt = 0; nt < 2; ++nt) acc[mt][nt] = (f32x4){0.f, 0.f, 0.f, 0.f};

    float4 aregs[4];
    auto issueA = [&](int t) {
#pragma unroll
        for (int i = 0; i < 4; ++i) {
            int idx = tid + i * 256;        // 0..1023
            int r = idx >> 5, c = idx & 31;
            int node = min(blkBase + r, NN - 1);
            aregs[i] = *reinterpret_cast<const float4*>(&emb[(size_t)node * DD + t * 128 + c * 4]);
        }
    };
    auto writeLDS = [&]() {
#pragma unroll
        for (int i = 0; i < 4; ++i) {
            int idx = tid + i * 256;
            int r = idx >> 5, c = idx & 31;
            ushort4 hv;
            hv.x = bf16rn(aregs[i].x);
            hv.y = bf16rn(aregs[i].y);
            hv.z = bf16rn(aregs[i].z);
            hv.w = bf16rn(aregs[i].w);
            int byte = (r * 256 + c * 8) ^ ((r & 7) << 4);
            *reinterpret_cast<ushort4*>(reinterpret_cast<char*>(Ah) + byte) = hv;
        }
    };

    issueA(0);
    writeLDS();
    __syncthreads();

#pragma unroll
    for (int t = 0; t < 3; ++t) {
        if (t < 2) issueA(t + 1);  // in flight across the whole compute phase

        short8 bh[2][2], ah[2][2];
        auto loadB = [&](int kt, int s) {
            int ks = t * 4 + kt;
#pragma unroll
            for (int nt = 0; nt < 2; ++nt) {
                int c = wn * 2 + nt;
                size_t off = ((size_t)(c * 12 + ks) * 64 + lane) * 8;
                bh[s][nt] = *reinterpret_cast<const short8*>(&W1h[off]);
            }
        };
        auto loadA = [&](int kt, int s) {
#pragma unroll
            for (int mt = 0; mt < 2; ++mt) {
                int row = mt * 16 + (lane & 15);
                int byte = (row * 256 + kt * 64 + ((lane >> 4) << 4)) ^ ((row & 7) << 4);
                ah[s][mt] = *reinterpret_cast<const short8*>(reinterpret_cast<const char*>(Ah) + byte);
            }
        };

        loadB(0, 0);
        loadA(0, 0);
#pragma unroll
        for (int kt = 0; kt < 4; ++kt) {
            const int cur = kt & 1, nxt = cur ^ 1;
            if (kt < 3) {
                loadB(kt + 1, nxt);
                loadA(kt + 1, nxt);
            }
#pragma unroll
            for (int mt = 0; mt < 2; ++mt)
#pragma unroll
                for (int nt = 0; nt < 2; ++nt)
                    acc[mt][nt] = __builtin_amdgcn_mfma_f32_16x16x32_bf16(ah[cur][mt], bh[cur][nt], acc[mt][nt], 0, 0, 0);
        }

        if (t < 2) {
            __syncthreads();   // all waves done reading tile t
            writeLDS();        // load wait lands here, hidden by compute above
            __syncthreads();
        }
    }

    // epilogue: v = relu(h + b1p); p[j] = sum over this wave's 32 cols of v*W2
    float b1v[2], w2v[2][KK];
#pragma unroll
    for (int nt = 0; nt < 2; ++nt) {
        int h = (wn * 2 + nt) * 16 + (lane & 15);
        b1v[nt] = b1p[h];
#pragma unroll
        for (int j = 0; j < KK; ++j) w2v[nt][j] = W2[h * KK + j];
    }
#pragma unroll
    for (int mt = 0; mt < 2; ++mt) {
        float p[4][KK];
#pragma unroll
        for (int r = 0; r < 4; ++r)
#pragma unroll
            for (int j = 0; j < KK; ++j) p[r][j] = 0.f;
#pragma unroll
        for (int nt = 0; nt < 2; ++nt)
#pragma unroll
            for (int r = 0; r < 4; ++r) {
                float v = fmaxf(acc[mt][nt][r] + b1v[nt], 0.f);
#pragma unroll
                for (int j = 0; j < KK; ++j) p[r][j] = fmaf(v, w2v[nt][j], p[r][j]);
            }
#pragma unroll
        for (int off = 1; off < 16; off <<= 1)
#pragma unroll
            for (int r = 0; r < 4; ++r)
#pragma unroll
                for (int j = 0; j < KK; ++j) p[r][j] += __shfl_xor(p[r][j], off, 64);
        if ((lane & 15) == 0) {
            int rowbase = mt * 16 + (lane >> 4) * 4;
#pragma unroll
            for (int r = 0; r < 4; ++r)
#pragma unroll
                for (int j = 0; j < KK; ++j) pbuf[rowbase + r][wn * 5 + j] = p[r][j];
        }
    }
    __syncthreads();
    if (tid < 32) {
        int node = blkBase + tid;
        if (node < NN) {
            float a[KK], an2 = 0.f;
#pragma unroll
            for (int j = 0; j < KK; ++j) {
                a[j] = pbuf[tid][j] + pbuf[tid][5 + j] + pbuf[tid][10 + j] +
                       pbuf[tid][15 + j] + b2[j];
                an2 = fmaf(a[j], a[j], an2);
            }
            float an = sqrtf(an2);
            bool valid = (an2 > 0.f) && isfinite(an);
            float g5[KK], ssum = 0.f;
#pragma unroll
            for (int j = 0; j < KK; ++j) {
                g5[j] = valid ? (a[j] / an) : RSQRT5;
                gout[j * NN + node] = g5[j];
                ssum += g5[j];
            }
            // fused walk step 1: state uniform INIT_VAL -> d = INIT * sum(g)
            float d = ssum * INIT_VAL;
#pragma unroll
            for (int j = 0; j < KK; ++j)
                atomicAdd(&sA[j * NN + nbrT[j * NN + node]], g5[j] * d);
        }
    }
}

// ---------------- persistent fused tail: walk2 + walk3 + norm + finalize ----------------
// 391 blocks (all trivially co-resident: needs 49 of 256 CUs). Manual spin
// grid-barriers on device-scope counters; g/nb loaded ONCE into registers.
__device__ __forceinline__ void gbar(unsigned* cnt, unsigned target) {
    __threadfence();                       // publish this thread's prior writes
    __syncthreads();
    if (threadIdx.x == 0) {
        atomicAdd(cnt, 1u);                // device-scope arrive
        while (__hip_atomic_load(cnt, __ATOMIC_ACQUIRE, __HIP_MEMORY_SCOPE_AGENT) < target) {}
    }
    __syncthreads();
}

__global__ __launch_bounds__(256) void walk_tail_kernel(
    const float* __restrict__ g, const int* __restrict__ nbrT,
    const float* __restrict__ sA, float* __restrict__ sB, float* __restrict__ sC,
    float* __restrict__ ssp, unsigned* __restrict__ cnt, float* __restrict__ out) {
    const int i = blockIdx.x * 256 + threadIdx.x;
    const bool act = i < NN;
    const unsigned nb_total = gridDim.x;

    float gj[KK];
    int nb[KK];
    float d1 = 0.f;
    // phase 0: load g/nb once, zero scatter dests, compute d1 = g . sA_row
    if (act) {
#pragma unroll
        for (int j = 0; j < KK; ++j) {
            gj[j] = g[j * NN + i];
            nb[j] = nbrT[j * NN + i];
            sB[j * NN + i] = 0.f;
            sC[j * NN + i] = 0.f;
            d1 = fmaf(gj[j], sA[j * NN + i], d1);
        }
    }
    gbar(cnt + 0, nb_total);               // sB/sC zeroed grid-wide

    // phase 1: walk step 2 scatter
    if (act) {
#pragma unroll
        for (int j = 0; j < KK; ++j)
            atomicAdd(&sB[j * NN + nb[j]], gj[j] * d1);
    }
    gbar(cnt + 1, nb_total);               // sB complete

    // phase 2: walk step 3 gather + scatter
    if (act) {
        float d2 = 0.f;
#pragma unroll
        for (int j = 0; j < KK; ++j) d2 = fmaf(gj[j], sB[j * NN + i], d2);
#pragma unroll
        for (int j = 0; j < KK; ++j)
            atomicAdd(&sC[j * NN + nb[j]], gj[j] * d2);
    }
    gbar(cnt + 2, nb_total);               // sC complete

    // phase 3: global sum of squares
    float s = 0.f;
    float cj[KK];
    if (act) {
#pragma unroll
        for (int j = 0; j < KK; ++j) {
            cj[j] = sC[j * NN + i];
            s = fmaf(cj[j], cj[j], s);
        }
    }
#pragma unroll
    for (int off = 32; off > 0; off >>= 1) s += __shfl_xor(s, off, 64);
    if ((threadIdx.x & 63) == 0) atomicAdd(ssp, s);
    gbar(cnt + 3, nb_total);               // ssp complete

    // phase 4: finalize
    if (act) {
        float nrm = sqrtf(ssp[0]);
        float t = 0.f;
#pragma unroll
        for (int j = 0; j < KK; ++j) t += fabsf(cj[j]);
        out[i] = (nrm > 0.f) ? (t / nrm) : (KK * INIT_VAL);
    }
}

extern "C" void kernel_launch(void* const* d_in, const int* in_sizes, int n_in,
                              void* d_out, int out_size, void* d_ws, size_t ws_size,
                              hipStream_t stream) {
    const float* emb = (const float*)d_in[0];
    const float* qv  = (const float*)d_in[1];
    const float* W1  = (const float*)d_in[2];
    const float* b1  = (const float*)d_in[3];
    const float* W2  = (const float*)d_in[4];
    const float* b2  = (const float*)d_in[5];
    const int*   nbr = (const int*)d_in[6];
    float* out = (float*)d_out;

    char* ws = (char*)d_ws;
    size_t off = 0;
    auto alloc = [&](size_t bytes) {
        char* p = ws + off;
        off += (bytes + 255) & ~(size_t)255;
        return p;
    };
    float*    b1p  = (float*)alloc(HH * sizeof(float));
    ushort*   W1h  = (ushort*)alloc((size_t)DD * HH * sizeof(ushort));
    float*    gbuf = (float*)alloc((size_t)KK * NN * sizeof(float));
    int*      nbrT = (int*)  alloc((size_t)KK * NN * sizeof(int));
    float*    sA   = (float*)alloc((size_t)KK * NN * sizeof(float));
    float*    sB   = (float*)alloc((size_t)KK * NN * sizeof(float));
    float*    sC   = (float*)alloc((size_t)KK * NN * sizeof(float));
    float*    ssp  = (float*)alloc(sizeof(float));
    unsigned* cnt  = (unsigned*)alloc(8 * sizeof(unsigned));

    const int nblk = (NN + 255) / 256;   // 391

    prep_kernel<<<25 + nblk, 256, 0, stream>>>(qv, W1, b1, nbr, b1p, W1h,
                                               nbrT, sA, ssp, cnt);
    // 3125 blocks x 32 nodes; mlp computes g AND performs walk step 1
    mlp_mfma_kernel<<<(NN + 31) / 32, 256, 0, stream>>>(emb, W1h, b1p, W2, b2,
                                                        nbrT, gbuf, sA);
    // single persistent dispatch: walk2 + walk3 + norm + finalize
    walk_tail_kernel<<<nblk, 256, 0, stream>>>(gbuf, nbrT, sA, sB, sC, ssp, cnt, out);
}

// Round 18
// 148.267 us; speedup vs baseline: 2.4641x; 2.4641x over previous
//
#include <hip/hip_runtime.h>
#include <hip/hip_bf16.h>
#include <math.h>

#define NN 100000
#define DD 384
#define HH 128
#define KK 5

typedef __attribute__((ext_vector_type(8))) short short8;
typedef __attribute__((ext_vector_type(4))) float f32x4;

constexpr float INIT_VAL = 1.4142135623730951e-3f; // 1/sqrt(N*K)
constexpr float RSQRT5   = 0.44721359549995793f;   // 1/sqrt(5)

// f32 -> bf16 round-to-nearest-even
__device__ __forceinline__ ushort bf16rn(float x) {
    unsigned u = __float_as_uint(x);
    return (ushort)((u + 0x7FFFu + ((u >> 16) & 1u)) >> 16);
}

// ---------------- fused prep ----------------
__global__ __launch_bounds__(256) void prep_kernel(
    const float* __restrict__ qv, const float* __restrict__ W1,
    const float* __restrict__ b1, const int* __restrict__ nbr,
    float* __restrict__ b1p, ushort* __restrict__ W1h,
    int* __restrict__ nbrT, float* __restrict__ sA, float* __restrict__ sB,
    float* __restrict__ sC, float* __restrict__ ssp) {
    const int b = blockIdx.x, tid = threadIdx.x;
    if (b == 0) {
        __shared__ float part[256];
        const int h = tid & 127, half = tid >> 7;
        float s = 0.f;
        const float* Wq = W1 + (size_t)(DD + half * 192) * HH + h;
        const float* qh = qv + half * 192;
#pragma unroll 8
        for (int k = 0; k < 192; ++k)
            s = fmaf(qh[k], Wq[(size_t)k * HH], s);
        part[tid] = s;
        __syncthreads();
        if (tid < HH) b1p[tid] = part[tid] + part[tid + 128] + b1[tid];
        if (tid == 0) ssp[0] = 0.f;
    } else if (b <= 24) {
        int t = (b - 1) * 256 + tid;       // t = (c*12 + ks)*64 + lane, t < 6144
        int l = t & 63;
        int ks = (t >> 6) % 12;
        int c = (t >> 6) / 12;             // hidden 16-col block 0..7
        int k0 = ks * 32 + ((l >> 4) << 3);
        int col = c * 16 + (l & 15);
#pragma unroll
        for (int e = 0; e < 8; ++e)
            W1h[(size_t)t * 8 + e] = bf16rn(W1[(size_t)(k0 + e) * HH + col]);
    } else {
        int i = (b - 25) * 256 + tid;
        if (i < NN) {
#pragma unroll
            for (int j = 0; j < KK; ++j) {
                nbrT[j * NN + i] = nbr[i * KK + j];
                sA[j * NN + i] = 0.f;
                sB[j * NN + i] = 0.f;
                sC[j * NN + i] = 0.f;
            }
        }
    }
}

// ---------------- single-bf16 MFMA MLP, 32-node tiles / max TLP + fused walk1 ----------------
// 3125 blocks x 32 nodes. 4 waves; wave w computes ALL 32 rows x its 32-col quarter.
// A staged f32->bf16(RNE) in 8 KB LDS (XOR swizzle); B pre-packed bf16 frags from L2.
__global__ __launch_bounds__(256) void mlp_mfma_kernel(
    const float* __restrict__ emb, const ushort* __restrict__ W1h,
    const float* __restrict__ b1p, const float* __restrict__ W2,
    const float* __restrict__ b2, const int* __restrict__ nbrT,
    float* __restrict__ gout /* [KK][NN] */, float* __restrict__ sA) {
    __shared__ __align__(16) ushort Ah[32 * 128];  // 8 KB
    __shared__ float pbuf[32][21];                 // 4 waves x 5 + pad

    const int tid = threadIdx.x;
    const int lane = tid & 63;
    const int wn = tid >> 6;   // col quarter 0..3
    const int blkBase = blockIdx.x * 32;

    f32x4 acc[2][2];
#pragma unroll
    for (int mt = 0; mt < 2; ++mt)
#pragma unroll
        for (int nt = 0; nt < 2; ++nt) acc[mt][nt] = (f32x4){0.f, 0.f, 0.f, 0.f};

    float4 aregs[4];
    auto issueA = [&](int t) {
#pragma unroll
        for (int i = 0; i < 4; ++i) {
            int idx = tid + i * 256;        // 0..1023
            int r = idx >> 5, c = idx & 31;
            int node = min(blkBase + r, NN - 1);
            aregs[i] = *reinterpret_cast<const float4*>(&emb[(size_t)node * DD + t * 128 + c * 4]);
        }
    };
    auto writeLDS = [&]() {
#pragma unroll
        for (int i = 0; i < 4; ++i) {
            int idx = tid + i * 256;
            int r = idx >> 5, c = idx & 31;
            ushort4 hv;
            hv.x = bf16rn(aregs[i].x);
            hv.y = bf16rn(aregs[i].y);
            hv.z = bf16rn(aregs[i].z);
            hv.w = bf16rn(aregs[i].w);
            int byte = (r * 256 + c * 8) ^ ((r & 7) << 4);
            *reinterpret_cast<ushort4*>(reinterpret_cast<char*>(Ah) + byte) = hv;
        }
    };

    issueA(0);
    writeLDS();
    __syncthreads();

#pragma unroll
    for (int t = 0; t < 3; ++t) {
        if (t < 2) issueA(t + 1);  // in flight across the whole compute phase

        short8 bh[2][2], ah[2][2];
        auto loadB = [&](int kt, int s) {
            int ks = t * 4 + kt;
#pragma unroll
            for (int nt = 0; nt < 2; ++nt) {
                int c = wn * 2 + nt;
                size_t off = ((size_t)(c * 12 + ks) * 64 + lane) * 8;
                bh[s][nt] = *reinterpret_cast<const short8*>(&W1h[off]);
            }
        };
        auto loadA = [&](int kt, int s) {
#pragma unroll
            for (int mt = 0; mt < 2; ++mt) {
                int row = mt * 16 + (lane & 15);
                int byte = (row * 256 + kt * 64 + ((lane >> 4) << 4)) ^ ((row & 7) << 4);
                ah[s][mt] = *reinterpret_cast<const short8*>(reinterpret_cast<const char*>(Ah) + byte);
            }
        };

        loadB(0, 0);
        loadA(0, 0);
#pragma unroll
        for (int kt = 0; kt < 4; ++kt) {
            const int cur = kt & 1, nxt = cur ^ 1;
            if (kt < 3) {
                loadB(kt + 1, nxt);
                loadA(kt + 1, nxt);
            }
#pragma unroll
            for (int mt = 0; mt < 2; ++mt)
#pragma unroll
                for (int nt = 0; nt < 2; ++nt)
                    acc[mt][nt] = __builtin_amdgcn_mfma_f32_16x16x32_bf16(ah[cur][mt], bh[cur][nt], acc[mt][nt], 0, 0, 0);
        }

        if (t < 2) {
            __syncthreads();   // all waves done reading tile t
            writeLDS();        // load wait lands here, hidden by compute above
            __syncthreads();
        }
    }

    // epilogue: v = relu(h + b1p); p[j] = sum over this wave's 32 cols of v*W2
    float b1v[2], w2v[2][KK];
#pragma unroll
    for (int nt = 0; nt < 2; ++nt) {
        int h = (wn * 2 + nt) * 16 + (lane & 15);
        b1v[nt] = b1p[h];
#pragma unroll
        for (int j = 0; j < KK; ++j) w2v[nt][j] = W2[h * KK + j];
    }
#pragma unroll
    for (int mt = 0; mt < 2; ++mt) {
        float p[4][KK];
#pragma unroll
        for (int r = 0; r < 4; ++r)
#pragma unroll
            for (int j = 0; j < KK; ++j) p[r][j] = 0.f;
#pragma unroll
        for (int nt = 0; nt < 2; ++nt)
#pragma unroll
            for (int r = 0; r < 4; ++r) {
                float v = fmaxf(acc[mt][nt][r] + b1v[nt], 0.f);
#pragma unroll
                for (int j = 0; j < KK; ++j) p[r][j] = fmaf(v, w2v[nt][j], p[r][j]);
            }
#pragma unroll
        for (int off = 1; off < 16; off <<= 1)
#pragma unroll
            for (int r = 0; r < 4; ++r)
#pragma unroll
                for (int j = 0; j < KK; ++j) p[r][j] += __shfl_xor(p[r][j], off, 64);
        if ((lane & 15) == 0) {
            int rowbase = mt * 16 + (lane >> 4) * 4;
#pragma unroll
            for (int r = 0; r < 4; ++r)
#pragma unroll
                for (int j = 0; j < KK; ++j) pbuf[rowbase + r][wn * 5 + j] = p[r][j];
        }
    }
    __syncthreads();
    if (tid < 32) {
        int node = blkBase + tid;
        if (node < NN) {
            float a[KK], an2 = 0.f;
#pragma unroll
            for (int j = 0; j < KK; ++j) {
                a[j] = pbuf[tid][j] + pbuf[tid][5 + j] + pbuf[tid][10 + j] +
                       pbuf[tid][15 + j] + b2[j];
                an2 = fmaf(a[j], a[j], an2);
            }
            float an = sqrtf(an2);
            bool valid = (an2 > 0.f) && isfinite(an);
            float g5[KK], ssum = 0.f;
#pragma unroll
            for (int j = 0; j < KK; ++j) {
                g5[j] = valid ? (a[j] / an) : RSQRT5;
                gout[j * NN + node] = g5[j];
                ssum += g5[j];
            }
            // fused walk step 1: state uniform INIT_VAL -> d = INIT * sum(g)
            float d = ssum * INIT_VAL;
#pragma unroll
            for (int j = 0; j < KK; ++j)
                atomicAdd(&sA[j * NN + nbrT[j * NN + node]], g5[j] * d);
        }
    }
}

// ---------------- walk step: s_p = g (g.u); scatter-add ----------------
__global__ void walk_step_kernel(const float* __restrict__ g, const int* __restrict__ nbrT,
                                 const float* __restrict__ u, float* __restrict__ v) {
    int i = blockIdx.x * blockDim.x + threadIdx.x;
    if (i >= NN) return;
    float gj[KK], d = 0.f;
#pragma unroll
    for (int j = 0; j < KK; ++j) {
        gj[j] = g[j * NN + i];
        d = fmaf(gj[j], u[j * NN + i], d);
    }
#pragma unroll
    for (int j = 0; j < KK; ++j)
        atomicAdd(&v[j * NN + nbrT[j * NN + i]], gj[j] * d);
}

// ---------------- global sum of squares (float4) ----------------
__global__ void norm_reduce_kernel(const float* __restrict__ u, float* __restrict__ ss) {
    int i = blockIdx.x * blockDim.x + threadIdx.x;
    const int total4 = (KK * NN) / 4;  // 125000
    float s = 0.f;
    for (int idx = i; idx < total4; idx += gridDim.x * blockDim.x) {
        float4 x = reinterpret_cast<const float4*>(u)[idx];
        s = fmaf(x.x, x.x, s);
        s = fmaf(x.y, x.y, s);
        s = fmaf(x.z, x.z, s);
        s = fmaf(x.w, x.w, s);
    }
#pragma unroll
    for (int off = 32; off > 0; off >>= 1) s += __shfl_xor(s, off, 64);
    if ((threadIdx.x & 63) == 0) atomicAdd(ss, s);
}

// ---------------- out[i] = sum_j |u[j][i]| / ||u|| ----------------
__global__ void finalize_kernel(const float* __restrict__ u, const float* __restrict__ ss,
                                float* __restrict__ out) {
    int i = blockIdx.x * blockDim.x + threadIdx.x;
    if (i >= NN) return;
    float s = 0.f;
#pragma unroll
    for (int j = 0; j < KK; ++j) s += fabsf(u[j * NN + i]);
    float nrm = sqrtf(*ss);
    out[i] = (nrm > 0.f) ? (s / nrm) : (KK * INIT_VAL);
}

extern "C" void kernel_launch(void* const* d_in, const int* in_sizes, int n_in,
                              void* d_out, int out_size, void* d_ws, size_t ws_size,
                              hipStream_t stream) {
    const float* emb = (const float*)d_in[0];
    const float* qv  = (const float*)d_in[1];
    const float* W1  = (const float*)d_in[2];
    const float* b1  = (const float*)d_in[3];
    const float* W2  = (const float*)d_in[4];
    const float* b2  = (const float*)d_in[5];
    const int*   nbr = (const int*)d_in[6];
    float* out = (float*)d_out;

    char* ws = (char*)d_ws;
    size_t off = 0;
    auto alloc = [&](size_t bytes) {
        char* p = ws + off;
        off += (bytes + 255) & ~(size_t)255;
        return p;
    };
    float*  b1p  = (float*)alloc(HH * sizeof(float));
    ushort* W1h  = (ushort*)alloc((size_t)DD * HH * sizeof(ushort));
    float*  gbuf = (float*)alloc((size_t)KK * NN * sizeof(float));
    int*    nbrT = (int*)  alloc((size_t)KK * NN * sizeof(int));
    float*  sA   = (float*)alloc((size_t)KK * NN * sizeof(float));
    float*  sB   = (float*)alloc((size_t)KK * NN * sizeof(float));
    float*  sC   = (float*)alloc((size_t)KK * NN * sizeof(float));
    float*  ssp  = (float*)alloc(sizeof(float));

    const int nblk = (NN + 255) / 256;   // 391

    prep_kernel<<<25 + nblk, 256, 0, stream>>>(qv, W1, b1, nbr, b1p, W1h,
                                               nbrT, sA, sB, sC, ssp);
    // 3125 blocks x 32 nodes; mlp computes g AND performs walk step 1
    mlp_mfma_kernel<<<(NN + 31) / 32, 256, 0, stream>>>(emb, W1h, b1p, W2, b2,
                                                        nbrT, gbuf, sA);

    walk_step_kernel<<<nblk, 256, 0, stream>>>(gbuf, nbrT, sA, sB);
    walk_step_kernel<<<nblk, 256, 0, stream>>>(gbuf, nbrT, sB, sC);

    norm_reduce_kernel<<<512, 256, 0, stream>>>(sC, ssp);
    finalize_kernel<<<nblk, 256, 0, stream>>>(sC, ssp, out);
}